// Round 1
// baseline (2482.757 us; speedup 1.0000x reference)
//
#include <hip/hip_runtime.h>
#include <math.h>

#define NBINS 256
#define NB2   (NBINS * NBINS)
#define BATCH 8
#define HDIM  512
#define WDIM  512

// Compute raised-cosine split for one value.
// v in [0,255] clipped; i0 = low bin, wl = weight low, wh = weight high.
__device__ __forceinline__ void bin_weights(float v, int& i0, float& wl, float& wh) {
    v = fminf(fmaxf(v, 0.0f), 255.0f);
    float f = fminf(floorf(v), 254.0f);
    float frac = v - f;
    float c = cosf(3.14159265358979323846f * frac);
    wl = 0.5f * (1.0f + c);
    wh = 1.0f - wl;
    i0 = (int)f;
}

// cband: for each (b, c): pairs (X[b,c,y,x], X[b,c,y+1,x+1]), y,x in [0,511)
__global__ void hist_cband(const float* __restrict__ X, float* __restrict__ out) {
    const int NPB = 511 * 511;
    const long long total = (long long)BATCH * 3 * NPB;
    long long stride = (long long)gridDim.x * blockDim.x;
    for (long long idx = (long long)blockIdx.x * blockDim.x + threadIdx.x;
         idx < total; idx += stride) {
        int bc = (int)(idx / NPB);   // b*3 + c
        int p  = (int)(idx % NPB);
        int y = p / 511, x = p % 511;
        const float* base = X + (long long)bc * (HDIM * WDIM);
        float va = base[y * WDIM + x];
        float vb = base[(y + 1) * WDIM + (x + 1)];
        int ix, iy; float wxl, wxh, wyl, wyh;
        bin_weights(va, ix, wxl, wxh);
        bin_weights(vb, iy, wyl, wyh);
        int b = bc / 3, c = bc % 3;
        float* h = out + (long long)(b * 6 + c) * NB2;
        atomicAdd(&h[ix * NBINS + iy],           wxl * wyl);
        atomicAdd(&h[ix * NBINS + iy + 1],       wxl * wyh);
        atomicAdd(&h[(ix + 1) * NBINS + iy],     wxh * wyl);
        atomicAdd(&h[(ix + 1) * NBINS + iy + 1], wxh * wyh);
    }
}

// cc: for each (b, pair p in {(0,1),(0,2),(1,2)}): pairs (X[b,i,k], X[b,j,k])
__global__ void hist_cc(const float* __restrict__ X, float* __restrict__ out) {
    const int NP = HDIM * WDIM;
    const long long total = (long long)BATCH * 3 * NP;
    long long stride = (long long)gridDim.x * blockDim.x;
    for (long long idx = (long long)blockIdx.x * blockDim.x + threadIdx.x;
         idx < total; idx += stride) {
        int bp = (int)(idx / NP);    // b*3 + p
        int k  = (int)(idx % NP);
        int b = bp / 3, p = bp % 3;
        int ci = (p == 2) ? 1 : 0;
        int cj = (p == 0) ? 1 : 2;
        const float* Xb = X + (long long)b * 3 * NP;
        float vi = Xb[(long long)ci * NP + k];
        float vj = Xb[(long long)cj * NP + k];
        int ix, iy; float wxl, wxh, wyl, wyh;
        bin_weights(vi, ix, wxl, wxh);
        bin_weights(vj, iy, wyl, wyh);
        float* h = out + (long long)(b * 6 + 3 + p) * NB2;
        atomicAdd(&h[ix * NBINS + iy],           wxl * wyl);
        atomicAdd(&h[ix * NBINS + iy + 1],       wxl * wyh);
        atomicAdd(&h[(ix + 1) * NBINS + iy],     wxh * wyl);
        atomicAdd(&h[(ix + 1) * NBINS + iy + 1], wxh * wyh);
    }
}

// One block per (b,ch) histogram: max over 65536 values -> vmax[ch]
__global__ void max_reduce(const float* __restrict__ out, float* __restrict__ vmax) {
    int ch = blockIdx.x;   // 0..47
    const float* h = out + (long long)ch * NB2;
    float m = 0.0f;        // hist values are >= 0
    for (int i = threadIdx.x; i < NB2; i += blockDim.x) m = fmaxf(m, h[i]);
    // wave-64 reduce
    for (int off = 32; off; off >>= 1) m = fmaxf(m, __shfl_down(m, off));
    __shared__ float s[16];
    int lane = threadIdx.x & 63, wid = threadIdx.x >> 6;
    if (lane == 0) s[wid] = m;
    __syncthreads();
    if (threadIdx.x == 0) {
        float mm = s[0];
        int nw = blockDim.x >> 6;
        for (int w = 1; w < nw; ++w) mm = fmaxf(mm, s[w]);
        vmax[ch] = mm;
    }
}

__global__ void normalize(float* __restrict__ out, const float* __restrict__ vmax) {
    const long long total = 48LL * NB2;
    long long stride = (long long)gridDim.x * blockDim.x;
    for (long long i = (long long)blockIdx.x * blockDim.x + threadIdx.x;
         i < total; i += stride) {
        int ch = (int)(i >> 16);
        out[i] = out[i] / vmax[ch];
    }
}

extern "C" void kernel_launch(void* const* d_in, const int* in_sizes, int n_in,
                              void* d_out, int out_size, void* d_ws, size_t ws_size,
                              hipStream_t stream) {
    const float* X = (const float*)d_in[0];
    float* out = (float*)d_out;
    float* vmax = (float*)d_ws;

    // Zero histograms every call (harness does not re-poison between replays).
    hipMemsetAsync(d_out, 0, (size_t)out_size * sizeof(float), stream);

    hist_cband<<<2048, 256, 0, stream>>>(X, out);
    hist_cc<<<2048, 256, 0, stream>>>(X, out);
    max_reduce<<<48, 256, 0, stream>>>(out, vmax);
    normalize<<<2048, 256, 0, stream>>>(out, vmax);
}

// Round 2
// 370.607 us; speedup vs baseline: 6.6992x; 6.6992x over previous
//
#include <hip/hip_runtime.h>
#include <math.h>

#define NBINS 256
#define NB2   (NBINS * NBINS)
#define BATCH 8
#define HDIM  512
#define WDIM  512
#define RRANGES 4
#define ROWS  (NBINS / RRANGES)   // 64 rows per range -> 64 KB LDS
#define SPLIT 2
#define TPB   1024
#define PI_F  3.14159265358979323846f

// blockIdx.x = (hist * RRANGES + r) * SPLIT + s
//   hist in [0,48): b = hist/6, ch = hist%6 (0-2 cband channel, 3-5 cc pair)
//   r: ix-row range [r*ROWS, (r+1)*ROWS)
//   s: pixel split half
__global__ __launch_bounds__(TPB) void hist_all(const float* __restrict__ X,
                                                float* __restrict__ out) {
    __shared__ float lh[ROWS * NBINS];   // 64 KB

    int blk  = blockIdx.x;
    int s    = blk & (SPLIT - 1);
    int rr   = (blk / SPLIT) & (RRANGES - 1);
    int hist = blk / (SPLIT * RRANGES);
    int b = hist / 6, ch = hist % 6;
    int LO = rr * ROWS;

    for (int k = threadIdx.x; k < ROWS * NBINS; k += TPB) lh[k] = 0.0f;
    __syncthreads();

    const int NP = HDIM * WDIM;

#define ACCUM(va_expr, vb_load_expr)                                          \
    {                                                                         \
        float a  = fminf(fmaxf((va_expr), 0.0f), 255.0f);                     \
        float fa = fminf(floorf(a), 254.0f);                                  \
        int   ix = (int)fa;                                                   \
        if (ix >= LO - 1 && ix < LO + ROWS) {                                 \
            float fraca = a - fa;                                             \
            float wxl = 0.5f * (1.0f + __cosf(PI_F * fraca));                 \
            float wxh = 1.0f - wxl;                                           \
            float vb = (vb_load_expr);                                        \
            float bb = fminf(fmaxf(vb, 0.0f), 255.0f);                        \
            float fb = fminf(floorf(bb), 254.0f);                             \
            int   iy = (int)fb;                                               \
            float fracb = bb - fb;                                            \
            float wyl = 0.5f * (1.0f + __cosf(PI_F * fracb));                 \
            float wyh = 1.0f - wyl;                                           \
            int row0 = ix - LO;                                               \
            int row1 = row0 + 1;                                              \
            if (row0 >= 0 && row0 < ROWS) {                                   \
                atomicAdd(&lh[row0 * NBINS + iy],     wxl * wyl);             \
                atomicAdd(&lh[row0 * NBINS + iy + 1], wxl * wyh);             \
            }                                                                 \
            if (row1 < ROWS) {                                                \
                atomicAdd(&lh[row1 * NBINS + iy],     wxh * wyl);             \
                atomicAdd(&lh[row1 * NBINS + iy + 1], wxh * wyh);             \
            }                                                                 \
        }                                                                     \
    }

    if (ch < 3) {
        // cband: pairs (X[b,ch,y,x], X[b,ch,y+1,x+1]), y,x in [0,511)
        const float* plane = X + (long long)(b * 3 + ch) * NP;
        const int N = 511 * 511;
        const int half = (N + SPLIT - 1) / SPLIT;
        int lo = s * half;
        int hi = min(N, lo + half);
        for (int i = lo + (int)threadIdx.x; i < hi; i += TPB) {
            int y = i / 511;
            int x = i - y * 511;
            int off = y * WDIM + x;
            ACCUM(plane[off], plane[off + WDIM + 1]);
        }
    } else {
        // cc: pairs (X[b,ci,k], X[b,cj,k])
        int p = ch - 3;
        int ci = (p == 2) ? 1 : 0;
        int cj = (p == 0) ? 1 : 2;
        const float* pli = X + (long long)(b * 3 + ci) * NP;
        const float* plj = X + (long long)(b * 3 + cj) * NP;
        const int half = NP / SPLIT;
        int lo = s * half;
        int hi = lo + half;
        for (int i = lo + (int)threadIdx.x; i < hi; i += TPB) {
            ACCUM(pli[i], plj[i]);
        }
    }
#undef ACCUM

    __syncthreads();
    // Flush: SPLIT blocks share each (hist, range) -> global atomicAdd (coalesced)
    float* dst = out + (long long)hist * NB2 + LO * NBINS;
    for (int k = threadIdx.x; k < ROWS * NBINS; k += TPB)
        atomicAdd(&dst[k], lh[k]);
}

// One block per histogram: max over 65536 values -> vmax[ch]
__global__ __launch_bounds__(1024) void max_reduce(const float* __restrict__ out,
                                                   float* __restrict__ vmax) {
    int ch = blockIdx.x;   // 0..47
    const float4* h = (const float4*)(out + (long long)ch * NB2);
    float m = 0.0f;        // hist values are >= 0
    for (int i = threadIdx.x; i < NB2 / 4; i += blockDim.x) {
        float4 v = h[i];
        m = fmaxf(m, fmaxf(fmaxf(v.x, v.y), fmaxf(v.z, v.w)));
    }
    for (int off = 32; off; off >>= 1) m = fmaxf(m, __shfl_down(m, off));
    __shared__ float sred[16];
    int lane = threadIdx.x & 63, wid = threadIdx.x >> 6;
    if (lane == 0) sred[wid] = m;
    __syncthreads();
    if (threadIdx.x == 0) {
        float mm = sred[0];
        int nw = blockDim.x >> 6;
        for (int w = 1; w < nw; ++w) mm = fmaxf(mm, sred[w]);
        vmax[ch] = mm;
    }
}

__global__ void normalize(float* __restrict__ out, const float* __restrict__ vmax) {
    const int total4 = 48 * NB2 / 4;
    int stride = gridDim.x * blockDim.x;
    float4* o4 = (float4*)out;
    for (int i = blockIdx.x * blockDim.x + threadIdx.x; i < total4; i += stride) {
        int ch = i >> 14;             // (i*4) >> 16
        float inv = 1.0f / vmax[ch];  // hist max always > 0
        float4 v = o4[i];
        v.x *= inv; v.y *= inv; v.z *= inv; v.w *= inv;
        o4[i] = v;
    }
}

extern "C" void kernel_launch(void* const* d_in, const int* in_sizes, int n_in,
                              void* d_out, int out_size, void* d_ws, size_t ws_size,
                              hipStream_t stream) {
    const float* X = (const float*)d_in[0];
    float* out = (float*)d_out;
    float* vmax = (float*)d_ws;

    // Zero histograms every call (flush uses atomicAdd; harness doesn't re-poison).
    hipMemsetAsync(d_out, 0, (size_t)out_size * sizeof(float), stream);

    hist_all<<<48 * RRANGES * SPLIT, TPB, 0, stream>>>(X, out);
    max_reduce<<<48, 1024, 0, stream>>>(out, vmax);
    normalize<<<1024, 256, 0, stream>>>(out, vmax);
}